// Round 1
// baseline (11049.628 us; speedup 1.0000x reference)
//
#include <hip/hip_runtime.h>
#include <hip/hip_bf16.h>

#define T_SEQ 2048
#define BATCH 2
#define CDIM 1024
#define VDIM 256
#define NHEAD 16
#define DHEAD 64
#define NLAYER 8
#define MROWS (BATCH * T_SEQ) /* 4096 */

// ---------------------------------------------------------------------------
// Generic f32 GEMM: C[M,N] = A[M,K] @ B[K,N] + bias[N] (+ addrow[(m%addmod)*N+n])
// BM=BN=64, BK=16, 256 threads, 4x4 per thread. All dims divide evenly here.
// ---------------------------------------------------------------------------
__global__ __launch_bounds__(256) void gemm_f32_kernel(
    const float* __restrict__ A, const float* __restrict__ B,
    const float* __restrict__ bias, const float* __restrict__ addrow,
    float* __restrict__ C, int M, int N, int K, int addmod)
{
    __shared__ float As[16][64];   // As[k][m] (transposed on store)
    __shared__ float Bs[16][68];   // Bs[k][n], padded

    const int tid = threadIdx.x;
    const int bn = blockIdx.x * 64;
    const int bm = blockIdx.y * 64;

    const int lrow = tid >> 2;        // 0..63  (A tile row)
    const int lkq  = (tid & 3) * 4;   // 0,4,8,12
    const int lkr  = tid >> 4;        // 0..15  (B tile row)
    const int lnq  = (tid & 15) * 4;  // 0..60
    const int ty   = tid >> 4;        // 0..15
    const int tx   = tid & 15;        // 0..15

    float acc[4][4];
#pragma unroll
    for (int i = 0; i < 4; ++i)
#pragma unroll
        for (int j = 0; j < 4; ++j) acc[i][j] = 0.f;

    for (int k0 = 0; k0 < K; k0 += 16) {
        __syncthreads();
        {
            float4 a4 = *(const float4*)&A[(size_t)(bm + lrow) * K + k0 + lkq];
            As[lkq + 0][lrow] = a4.x;
            As[lkq + 1][lrow] = a4.y;
            As[lkq + 2][lrow] = a4.z;
            As[lkq + 3][lrow] = a4.w;
            *(float4*)&Bs[lkr][lnq] =
                *(const float4*)&B[(size_t)(k0 + lkr) * N + bn + lnq];
        }
        __syncthreads();
#pragma unroll
        for (int kk = 0; kk < 16; ++kk) {
            const float4 a = *(const float4*)&As[kk][ty * 4];
            const float4 b = *(const float4*)&Bs[kk][tx * 4];
            acc[0][0] += a.x * b.x; acc[0][1] += a.x * b.y; acc[0][2] += a.x * b.z; acc[0][3] += a.x * b.w;
            acc[1][0] += a.y * b.x; acc[1][1] += a.y * b.y; acc[1][2] += a.y * b.z; acc[1][3] += a.y * b.w;
            acc[2][0] += a.z * b.x; acc[2][1] += a.z * b.y; acc[2][2] += a.z * b.z; acc[2][3] += a.z * b.w;
            acc[3][0] += a.w * b.x; acc[3][1] += a.w * b.y; acc[3][2] += a.w * b.z; acc[3][3] += a.w * b.w;
        }
    }

    const int ncol = bn + tx * 4;
    const float4 bv = *(const float4*)&bias[ncol];
#pragma unroll
    for (int i = 0; i < 4; ++i) {
        const int mrow = bm + ty * 4 + i;
        float4 o;
        o.x = acc[i][0] + bv.x;
        o.y = acc[i][1] + bv.y;
        o.z = acc[i][2] + bv.z;
        o.w = acc[i][3] + bv.w;
        if (addrow) {
            const float4 p = *(const float4*)&addrow[(size_t)(mrow % addmod) * N + ncol];
            o.x += p.x; o.y += p.y; o.z += p.z; o.w += p.w;
        }
        *(float4*)&C[(size_t)mrow * N + ncol] = o;
    }
}

// ---------------------------------------------------------------------------
// Flash attention, f32. One block = 64 query rows of one (b, head).
// qkv layout: [4096][3072], q at col h*64, k at 1024+h*64, v at 2048+h*64.
// 256 threads: thread = (row r=tid>>2, quarter q4=tid&3).
// S-columns per thread interleaved (cc = 4c+q4) for bank-conflict-free K reads.
// ---------------------------------------------------------------------------
__global__ __launch_bounds__(256) void attn_f32_kernel(
    const float* __restrict__ qkv, float* __restrict__ y)
{
    __shared__ float Ks[64][68];
    __shared__ float Vs[64][68];
    __shared__ float Ps[64][68];

    const int tid = threadIdx.x;
    const int r   = tid >> 2;     // query row in tile, 0..63
    const int q4  = tid & 3;      // 0..3
    const int d0  = q4 * 16;      // owned output dims d0..d0+15

    const int bh = blockIdx.y;
    const int b  = bh >> 4;
    const int hh = bh & 15;
    const int t0 = blockIdx.x * 64;

    const float* base  = qkv + (size_t)b * T_SEQ * 3072 + (size_t)hh * 64;
    const float* kbase = base + 1024;
    const float* vbase = base + 2048;

    // q row -> registers (4 threads/row read same 256B; L1-served)
    float qreg[64];
    {
        const float* qsrc = base + (size_t)(t0 + r) * 3072;
#pragma unroll
        for (int j = 0; j < 64; j += 4) {
            const float4 t4 = *(const float4*)(qsrc + j);
            qreg[j] = t4.x; qreg[j + 1] = t4.y; qreg[j + 2] = t4.z; qreg[j + 3] = t4.w;
        }
    }

    float m = -3.0e38f, l = 0.f;
    float acc[16];
#pragma unroll
    for (int i = 0; i < 16; ++i) acc[i] = 0.f;

    for (int s0 = 0; s0 < T_SEQ; s0 += 64) {
        __syncthreads();  // previous iter's readers done before overwrite
        {
            const float* ksrc = kbase + (size_t)(s0 + r) * 3072 + d0;
            const float* vsrc = vbase + (size_t)(s0 + r) * 3072 + d0;
#pragma unroll
            for (int j = 0; j < 16; j += 4) {
                *(float4*)&Ks[r][d0 + j] = *(const float4*)(ksrc + j);
                *(float4*)&Vs[r][d0 + j] = *(const float4*)(vsrc + j);
            }
        }
        __syncthreads();

        // S[r][cc] for cc = 4c+q4, c=0..15
        float sv[16];
        float tmax = -3.0e38f;
#pragma unroll
        for (int c = 0; c < 16; ++c) {
            const int cc = c * 4 + q4;
            float dot = 0.f;
#pragma unroll
            for (int kk = 0; kk < 64; kk += 4) {
                const float4 kb = *(const float4*)&Ks[cc][kk];
                dot += qreg[kk] * kb.x + qreg[kk + 1] * kb.y
                     + qreg[kk + 2] * kb.z + qreg[kk + 3] * kb.w;
            }
            sv[c] = dot * 0.125f;
            tmax = fmaxf(tmax, sv[c]);
        }
        // reduce max/sum across the 4 threads of this row (lanes differ in bits 0..1)
        tmax = fmaxf(tmax, __shfl_xor(tmax, 1));
        tmax = fmaxf(tmax, __shfl_xor(tmax, 2));
        const float mnew = fmaxf(m, tmax);
        const float corr = __expf(m - mnew);
        float psum = 0.f;
#pragma unroll
        for (int c = 0; c < 16; ++c) {
            const float p = __expf(sv[c] - mnew);
            Ps[r][c * 4 + q4] = p;
            psum += p;
        }
        psum += __shfl_xor(psum, 1);
        psum += __shfl_xor(psum, 2);
        l = l * corr + psum;
        m = mnew;
#pragma unroll
        for (int i = 0; i < 16; ++i) acc[i] *= corr;
        __syncthreads();  // Ps visible

        // acc[d] += sum_s P[r][s] * V[s][d0+d]
#pragma unroll
        for (int s = 0; s < 64; ++s) {
            const float p = Ps[r][s];
            const float4 v0 = *(const float4*)&Vs[s][d0 + 0];
            const float4 v1 = *(const float4*)&Vs[s][d0 + 4];
            const float4 v2 = *(const float4*)&Vs[s][d0 + 8];
            const float4 v3 = *(const float4*)&Vs[s][d0 + 12];
            acc[0]  += p * v0.x; acc[1]  += p * v0.y; acc[2]  += p * v0.z; acc[3]  += p * v0.w;
            acc[4]  += p * v1.x; acc[5]  += p * v1.y; acc[6]  += p * v1.z; acc[7]  += p * v1.w;
            acc[8]  += p * v2.x; acc[9]  += p * v2.y; acc[10] += p * v2.z; acc[11] += p * v2.w;
            acc[12] += p * v3.x; acc[13] += p * v3.y; acc[14] += p * v3.z; acc[15] += p * v3.w;
        }
    }

    const float inv = 1.f / l;
    float* dst = y + (size_t)(b * T_SEQ + t0 + r) * CDIM + hh * 64 + d0;
#pragma unroll
    for (int i = 0; i < 16; i += 4) {
        float4 o = make_float4(acc[i] * inv, acc[i + 1] * inv, acc[i + 2] * inv, acc[i + 3] * inv);
        *(float4*)(dst + i) = o;
    }
}

// ---------------------------------------------------------------------------
// LayerNorm over last dim (1024). One block (256 thr) per row.
// ---------------------------------------------------------------------------
__global__ __launch_bounds__(256) void ln_kernel(
    const float* __restrict__ h, const float* __restrict__ gamma,
    const float* __restrict__ beta, float* __restrict__ out)
{
    const int row = blockIdx.x;
    const int tid = threadIdx.x;
    const float* x = h + (size_t)row * CDIM;

    const float4 v = *(const float4*)&x[tid * 4];
    float s  = v.x + v.y + v.z + v.w;
    float ss = v.x * v.x + v.y * v.y + v.z * v.z + v.w * v.w;
#pragma unroll
    for (int off = 1; off < 64; off <<= 1) {
        s  += __shfl_xor(s, off);
        ss += __shfl_xor(ss, off);
    }
    __shared__ float rs[4], rss[4];
    const int wid = tid >> 6;
    if ((tid & 63) == 0) { rs[wid] = s; rss[wid] = ss; }
    __syncthreads();
    s  = rs[0] + rs[1] + rs[2] + rs[3];
    ss = rss[0] + rss[1] + rss[2] + rss[3];

    const float mu   = s * (1.f / (float)CDIM);
    const float var  = ss * (1.f / (float)CDIM) - mu * mu;
    const float rstd = rsqrtf(var + 1e-5f);

    const float4 g  = *(const float4*)&gamma[tid * 4];
    const float4 be = *(const float4*)&beta[tid * 4];
    float4 o;
    o.x = (v.x - mu) * rstd * g.x + be.x;
    o.y = (v.y - mu) * rstd * g.y + be.y;
    o.z = (v.z - mu) * rstd * g.z + be.z;
    o.w = (v.w - mu) * rstd * g.w + be.w;
    *(float4*)&out[(size_t)row * CDIM + tid * 4] = o;
}

// ---------------------------------------------------------------------------
extern "C" void kernel_launch(void* const* d_in, const int* in_sizes, int n_in,
                              void* d_out, int out_size, void* d_ws, size_t ws_size,
                              hipStream_t stream)
{
    const float* x      = (const float*)d_in[0];
    const float* W_emb  = (const float*)d_in[1];
    const float* b_emb  = (const float*)d_in[2];
    const float* pos    = (const float*)d_in[3];
    const float* Wqkv   = (const float*)d_in[4];
    const float* bqkv   = (const float*)d_in[5];
    const float* Wproj  = (const float*)d_in[6];
    const float* bproj  = (const float*)d_in[7];
    const float* gamma  = (const float*)d_in[8];
    const float* beta   = (const float*)d_in[9];
    const float* W_out  = (const float*)d_in[10];
    const float* b_out  = (const float*)d_in[11];
    float* out = (float*)d_out;

    float* h   = (float*)d_ws;                          // 4096*1024
    float* qkv = h + (size_t)MROWS * CDIM;              // 4096*3072
    float* y   = qkv + (size_t)MROWS * 3 * CDIM;        // 4096*1024

    const dim3 blk(256);

    // h = x @ W_emb + b_emb + pos  (M=4096, K=256, N=1024)
    gemm_f32_kernel<<<dim3(CDIM / 64, MROWS / 64), blk, 0, stream>>>(
        x, W_emb, b_emb, pos, h, MROWS, CDIM, VDIM, T_SEQ);

    for (int l = 0; l < NLAYER; ++l) {
        // qkv = h @ Wqkv[l] + bqkv[l]  (M=4096, K=1024, N=3072)
        gemm_f32_kernel<<<dim3(3 * CDIM / 64, MROWS / 64), blk, 0, stream>>>(
            h, Wqkv + (size_t)l * CDIM * 3 * CDIM, bqkv + (size_t)l * 3 * CDIM,
            nullptr, qkv, MROWS, 3 * CDIM, CDIM, 1);
        // y = attention(qkv)
        attn_f32_kernel<<<dim3(T_SEQ / 64, BATCH * NHEAD), blk, 0, stream>>>(qkv, y);
        // h = y @ Wproj[l] + bproj[l]  (M=4096, K=1024, N=1024)
        gemm_f32_kernel<<<dim3(CDIM / 64, MROWS / 64), blk, 0, stream>>>(
            y, Wproj + (size_t)l * CDIM * CDIM, bproj + (size_t)l * CDIM,
            nullptr, h, MROWS, CDIM, CDIM, 1);
    }

    // y = LayerNorm(h) * gamma + beta
    ln_kernel<<<dim3(MROWS), blk, 0, stream>>>(h, gamma, beta, y);
    // out = y @ W_out + b_out  (M=4096, K=1024, N=256)
    gemm_f32_kernel<<<dim3(VDIM / 64, MROWS / 64), blk, 0, stream>>>(
        y, W_out, b_out, nullptr, out, MROWS, VDIM, CDIM, 1);
}

// Round 2
// 4815.026 us; speedup vs baseline: 2.2948x; 2.2948x over previous
//
#include <hip/hip_runtime.h>
#include <hip/hip_bf16.h>

#define T_SEQ 2048
#define BATCH 2
#define CDIM 1024
#define VDIM 256
#define NHEAD 16
#define DHEAD 64
#define NLAYER 8
#define MROWS (BATCH * T_SEQ) /* 4096 */

typedef __attribute__((ext_vector_type(8))) short bf16x8;
typedef __attribute__((ext_vector_type(4))) float f32x4;
typedef __attribute__((ext_vector_type(4))) int i32x4;

// v_perm_b32: sel byte 0-3 -> from 2nd arg (S1), 4-7 -> from 1st arg (S0)
#define SELHI 0x07060302u  // [a.b3 a.b2 b.b3 b.b2] : top16(a)<<16 | top16(b)
#define SELLO 0x05040100u  // [a.b1 a.b0 b.b1 b.b0] : low16(a)<<16 | low16(b)

__device__ __forceinline__ uint prm(uint a, uint b, uint s) { return __builtin_amdgcn_perm(a, b, s); }

// split f32 -> (bf16 hi | bf16 lo) packed in one u32. hi = trunc-bf16(x), lo = trunc-bf16(x - hi).
__device__ __forceinline__ uint packsplit(float x) {
    uint xb = __float_as_uint(x);
    float hf = __uint_as_float(xb & 0xffff0000u);
    float d  = x - hf;                      // exact
    return prm(xb, __float_as_uint(d), SELHI);
}

__device__ __forceinline__ bf16x8 asb(i32x4 v) {
    union { i32x4 i; bf16x8 b; } u; u.i = v; return u.b;
}

// ---------------------------------------------------------------------------
// Generic f32 GEMM: C[M,N] = A[M,K] @ B[K,N] + bias[N] (+ addrow)
// out_mode 0: f32 output (+ optional addrow). out_mode 1: packed hi/lo u32.
// ---------------------------------------------------------------------------
__global__ __launch_bounds__(256) void gemm_f32_kernel(
    const float* __restrict__ A, const float* __restrict__ B,
    const float* __restrict__ bias, const float* __restrict__ addrow,
    float* __restrict__ C, int M, int N, int K, int addmod, int out_mode)
{
    __shared__ float As[16][64];
    __shared__ float Bs[16][68];

    const int tid = threadIdx.x;
    const int bn = blockIdx.x * 64;
    const int bm = blockIdx.y * 64;

    const int lrow = tid >> 2;
    const int lkq  = (tid & 3) * 4;
    const int lkr  = tid >> 4;
    const int lnq  = (tid & 15) * 4;
    const int ty   = tid >> 4;
    const int tx   = tid & 15;

    float acc[4][4];
#pragma unroll
    for (int i = 0; i < 4; ++i)
#pragma unroll
        for (int j = 0; j < 4; ++j) acc[i][j] = 0.f;

    for (int k0 = 0; k0 < K; k0 += 16) {
        __syncthreads();
        {
            float4 a4 = *(const float4*)&A[(size_t)(bm + lrow) * K + k0 + lkq];
            As[lkq + 0][lrow] = a4.x;
            As[lkq + 1][lrow] = a4.y;
            As[lkq + 2][lrow] = a4.z;
            As[lkq + 3][lrow] = a4.w;
            *(float4*)&Bs[lkr][lnq] =
                *(const float4*)&B[(size_t)(k0 + lkr) * N + bn + lnq];
        }
        __syncthreads();
#pragma unroll
        for (int kk = 0; kk < 16; ++kk) {
            const float4 a = *(const float4*)&As[kk][ty * 4];
            const float4 b = *(const float4*)&Bs[kk][tx * 4];
            acc[0][0] += a.x * b.x; acc[0][1] += a.x * b.y; acc[0][2] += a.x * b.z; acc[0][3] += a.x * b.w;
            acc[1][0] += a.y * b.x; acc[1][1] += a.y * b.y; acc[1][2] += a.y * b.z; acc[1][3] += a.y * b.w;
            acc[2][0] += a.z * b.x; acc[2][1] += a.z * b.y; acc[2][2] += a.z * b.z; acc[2][3] += a.z * b.w;
            acc[3][0] += a.w * b.x; acc[3][1] += a.w * b.y; acc[3][2] += a.w * b.z; acc[3][3] += a.w * b.w;
        }
    }

    const int ncol = bn + tx * 4;
    const float4 bv = *(const float4*)&bias[ncol];
#pragma unroll
    for (int i = 0; i < 4; ++i) {
        const int mrow = bm + ty * 4 + i;
        float4 o;
        o.x = acc[i][0] + bv.x;
        o.y = acc[i][1] + bv.y;
        o.z = acc[i][2] + bv.z;
        o.w = acc[i][3] + bv.w;
        if (out_mode == 0) {
            if (addrow) {
                const float4 p = *(const float4*)&addrow[(size_t)(mrow % addmod) * N + ncol];
                o.x += p.x; o.y += p.y; o.z += p.z; o.w += p.w;
            }
            *(float4*)&C[(size_t)mrow * N + ncol] = o;
        } else {
            uint4 pk;
            pk.x = packsplit(o.x); pk.y = packsplit(o.y);
            pk.z = packsplit(o.z); pk.w = packsplit(o.w);
            *(uint4*)&((uint*)C)[(size_t)mrow * N + ncol] = pk;
        }
    }
}

// ---------------------------------------------------------------------------
// Flash attention with MFMA bf16x2 (3-term compensated products).
// Swapped orientation: S^T = K·Q^T per wave ([64 s][16 q]) so softmax is
// lane-local (col=q=lane&15) and P^T regs feed PV's B-operand directly.
// O^T[d][q] = V^T·P^T. No max-subtraction (|logit| << 1 by construction).
// Block: 256 thr = 4 waves; wave w owns q rows [t0+16w, t0+16w+16).
// ---------------------------------------------------------------------------
__global__ __launch_bounds__(256) void attn_mfma_kernel(
    const uint* __restrict__ qkv, float* __restrict__ y)
{
    // frag-linear K/V: [subtile][k-chunk][lane][8 bf16] -> conflict-free b128
    __shared__ __align__(16) short khi[4][2][64][8];
    __shared__ __align__(16) short klo[4][2][64][8];
    __shared__ __align__(16) short vhi[4][2][64][8];
    __shared__ __align__(16) short vlo[4][2][64][8];
    __shared__ uint vpl[64][68];  // V tile [s][d] staging for transpose

    const int tid  = threadIdx.x;
    const int w    = tid >> 6;
    const int lane = tid & 63;
    const int x    = lane & 15;   // q column (B/D frag), d row (A frag)
    const int gl   = lane >> 4;
    const int bh = blockIdx.y, b = bh >> 4, hh = bh & 15;
    const int t0 = blockIdx.x * 64;

    // ---- Q fragments (B-operand: col=q=x, k=d), hi/lo, 2 k-chunks ----
    i32x4 qhi[2], qlo[2];
    {
        const uint* qp = qkv + (size_t)(b * T_SEQ + t0 + 16 * w + x) * 3072 + hh * 64;
#pragma unroll
        for (int ch = 0; ch < 2; ++ch) {
            uint4 a0 = *(const uint4*)(qp + 32 * ch + 4 * gl);
            uint4 a1 = *(const uint4*)(qp + 32 * ch + 16 + 4 * gl);
            qhi[ch][0] = prm(a0.y, a0.x, SELHI); qhi[ch][1] = prm(a0.w, a0.z, SELHI);
            qhi[ch][2] = prm(a1.y, a1.x, SELHI); qhi[ch][3] = prm(a1.w, a1.z, SELHI);
            qlo[ch][0] = prm(a0.y, a0.x, SELLO); qlo[ch][1] = prm(a0.w, a0.z, SELLO);
            qlo[ch][2] = prm(a1.y, a1.x, SELLO); qlo[ch][3] = prm(a1.w, a1.z, SELLO);
        }
    }

    // staging roles
    const int rK = tid >> 2, q4 = tid & 3;
    const int sc_s = rK >> 4, xk = rK & 15, chS = q4 >> 1, h2 = q4 & 1;

    f32x4 oacc[4];
#pragma unroll
    for (int i = 0; i < 4; ++i) oacc[i] = (f32x4){0.f, 0.f, 0.f, 0.f};
    float lsum = 0.f;

    const float SCL2 = 0.18033688011f;  // (1/8) * log2(e)

    for (int s0 = 0; s0 < T_SEQ; s0 += 64) {
        __syncthreads();
        // ---- stage K (frag-linear) + V (plain) ----
        {
            const uint* kp = qkv + (size_t)(b * T_SEQ + s0 + rK) * 3072 + 1024 + hh * 64 + 16 * q4;
            uint4 k0 = ((const uint4*)kp)[0], k1 = ((const uint4*)kp)[1];
            uint4 k2 = ((const uint4*)kp)[2], k3 = ((const uint4*)kp)[3];
            uint uu[16] = {k0.x, k0.y, k0.z, k0.w, k1.x, k1.y, k1.z, k1.w,
                           k2.x, k2.y, k2.z, k2.w, k3.x, k3.y, k3.z, k3.w};
#pragma unroll
            for (int g = 0; g < 4; ++g) {
                int2 hi2, lo2;
                hi2.x = (int)prm(uu[4 * g + 1], uu[4 * g + 0], SELHI);
                hi2.y = (int)prm(uu[4 * g + 3], uu[4 * g + 2], SELHI);
                lo2.x = (int)prm(uu[4 * g + 1], uu[4 * g + 0], SELLO);
                lo2.y = (int)prm(uu[4 * g + 3], uu[4 * g + 2], SELLO);
                *(int2*)&khi[sc_s][chS][16 * g + xk][4 * h2] = hi2;
                *(int2*)&klo[sc_s][chS][16 * g + xk][4 * h2] = lo2;
            }
            const uint* vp = qkv + (size_t)(b * T_SEQ + s0 + rK) * 3072 + 2048 + hh * 64 + 16 * q4;
            uint4 w0 = ((const uint4*)vp)[0], w1 = ((const uint4*)vp)[1];
            uint4 w2 = ((const uint4*)vp)[2], w3 = ((const uint4*)vp)[3];
            *(uint4*)&vpl[rK][16 * q4 + 0]  = w0;
            *(uint4*)&vpl[rK][16 * q4 + 4]  = w1;
            *(uint4*)&vpl[rK][16 * q4 + 8]  = w2;
            *(uint4*)&vpl[rK][16 * q4 + 12] = w3;
        }
        __syncthreads();
        // ---- repack V -> frag-linear (A-operand: row=d, k=s) ----
#pragma unroll
        for (int t2 = 0; t2 < 2; ++t2) {
            const int G = tid + 256 * t2;
            const int lt = G & 63, chv = (G >> 6) & 1, dm = G >> 7;
            const int glt = lt >> 4, xt = lt & 15, col = 16 * dm + xt;
            uint v0 = vpl[32 * chv + 4 * glt + 0][col];
            uint v1 = vpl[32 * chv + 4 * glt + 1][col];
            uint v2 = vpl[32 * chv + 4 * glt + 2][col];
            uint v3 = vpl[32 * chv + 4 * glt + 3][col];
            uint v4 = vpl[32 * chv + 4 * glt + 16][col];
            uint v5 = vpl[32 * chv + 4 * glt + 17][col];
            uint v6 = vpl[32 * chv + 4 * glt + 18][col];
            uint v7 = vpl[32 * chv + 4 * glt + 19][col];
            i32x4 hi4, lo4;
            hi4[0] = (int)prm(v1, v0, SELHI); hi4[1] = (int)prm(v3, v2, SELHI);
            hi4[2] = (int)prm(v5, v4, SELHI); hi4[3] = (int)prm(v7, v6, SELHI);
            lo4[0] = (int)prm(v1, v0, SELLO); lo4[1] = (int)prm(v3, v2, SELLO);
            lo4[2] = (int)prm(v5, v4, SELLO); lo4[3] = (int)prm(v7, v6, SELLO);
            *(i32x4*)&vhi[dm][chv][lt][0] = hi4;
            *(i32x4*)&vlo[dm][chv][lt][0] = lo4;
        }

        // ---- S^T = K·Q^T (per wave: [64 s][16 q]) + exp ----
        f32x4 pcur[4];
#pragma unroll
        for (int sc = 0; sc < 4; ++sc) {
            f32x4 s4 = (f32x4){0.f, 0.f, 0.f, 0.f};
#pragma unroll
            for (int ch = 0; ch < 2; ++ch) {
                bf16x8 kh = *(const bf16x8*)&khi[sc][ch][lane][0];
                bf16x8 kl = *(const bf16x8*)&klo[sc][ch][lane][0];
                s4 = __builtin_amdgcn_mfma_f32_16x16x32_bf16(kh, asb(qhi[ch]), s4, 0, 0, 0);
                s4 = __builtin_amdgcn_mfma_f32_16x16x32_bf16(kh, asb(qlo[ch]), s4, 0, 0, 0);
                s4 = __builtin_amdgcn_mfma_f32_16x16x32_bf16(kl, asb(qhi[ch]), s4, 0, 0, 0);
            }
            f32x4 p;
            p[0] = __expf(s4[0] * 0.125f);
            p[1] = __expf(s4[1] * 0.125f);
            p[2] = __expf(s4[2] * 0.125f);
            p[3] = __expf(s4[3] * 0.125f);
            lsum += p[0] + p[1] + p[2] + p[3];
            pcur[sc] = p;
        }
        (void)SCL2;

        // ---- P^T -> bf16 hi/lo B-fragments (in-register, no LDS) ----
        i32x4 pfh[2], pfl[2];
#pragma unroll
        for (int c = 0; c < 2; ++c) {
            f32x4 pa = pcur[2 * c], pb = pcur[2 * c + 1];
            uint a0 = __float_as_uint(pa[0]), a1 = __float_as_uint(pa[1]);
            uint a2 = __float_as_uint(pa[2]), a3 = __float_as_uint(pa[3]);
            uint b0 = __float_as_uint(pb[0]), b1 = __float_as_uint(pb[1]);
            uint b2 = __float_as_uint(pb[2]), b3 = __float_as_uint(pb[3]);
            pfh[c][0] = (int)prm(a1, a0, SELHI); pfh[c][1] = (int)prm(a3, a2, SELHI);
            pfh[c][2] = (int)prm(b1, b0, SELHI); pfh[c][3] = (int)prm(b3, b2, SELHI);
            float d0 = pa[0] - __uint_as_float(a0 & 0xffff0000u);
            float d1 = pa[1] - __uint_as_float(a1 & 0xffff0000u);
            float d2 = pa[2] - __uint_as_float(a2 & 0xffff0000u);
            float d3 = pa[3] - __uint_as_float(a3 & 0xffff0000u);
            float e0 = pb[0] - __uint_as_float(b0 & 0xffff0000u);
            float e1 = pb[1] - __uint_as_float(b1 & 0xffff0000u);
            float e2 = pb[2] - __uint_as_float(b2 & 0xffff0000u);
            float e3 = pb[3] - __uint_as_float(b3 & 0xffff0000u);
            pfl[c][0] = (int)prm(__float_as_uint(d1), __float_as_uint(d0), SELHI);
            pfl[c][1] = (int)prm(__float_as_uint(d3), __float_as_uint(d2), SELHI);
            pfl[c][2] = (int)prm(__float_as_uint(e1), __float_as_uint(e0), SELHI);
            pfl[c][3] = (int)prm(__float_as_uint(e3), __float_as_uint(e2), SELHI);
        }
        __syncthreads();  // V repack complete before PV

        // ---- O^T += V^T·P^T ----
#pragma unroll
        for (int dm = 0; dm < 4; ++dm) {
#pragma unroll
            for (int ch = 0; ch < 2; ++ch) {
                bf16x8 vh = *(const bf16x8*)&vhi[dm][ch][lane][0];
                bf16x8 vl = *(const bf16x8*)&vlo[dm][ch][lane][0];
                oacc[dm] = __builtin_amdgcn_mfma_f32_16x16x32_bf16(vh, asb(pfh[ch]), oacc[dm], 0, 0, 0);
                oacc[dm] = __builtin_amdgcn_mfma_f32_16x16x32_bf16(vh, asb(pfl[ch]), oacc[dm], 0, 0, 0);
                oacc[dm] = __builtin_amdgcn_mfma_f32_16x16x32_bf16(vl, asb(pfh[ch]), oacc[dm], 0, 0, 0);
            }
        }
    }

    // l covers only this lane's gl-block of s -> reduce across gl groups
    lsum += __shfl_xor(lsum, 16);
    lsum += __shfl_xor(lsum, 32);
    const float invl = 1.f / lsum;

    float* yp = y + (size_t)(b * T_SEQ + t0 + 16 * w + x) * CDIM + hh * 64;
#pragma unroll
    for (int dm = 0; dm < 4; ++dm) {
        f32x4 o = oacc[dm];
        o[0] *= invl; o[1] *= invl; o[2] *= invl; o[3] *= invl;
        *(f32x4*)(yp + 16 * dm + 4 * gl) = o;
    }
}

// ---------------------------------------------------------------------------
// LayerNorm over last dim (1024). One block (256 thr) per row.
// ---------------------------------------------------------------------------
__global__ __launch_bounds__(256) void ln_kernel(
    const float* __restrict__ h, const float* __restrict__ gamma,
    const float* __restrict__ beta, float* __restrict__ out)
{
    const int row = blockIdx.x;
    const int tid = threadIdx.x;
    const float* xr = h + (size_t)row * CDIM;

    const float4 v = *(const float4*)&xr[tid * 4];
    float s  = v.x + v.y + v.z + v.w;
    float ss = v.x * v.x + v.y * v.y + v.z * v.z + v.w * v.w;
#pragma unroll
    for (int off = 1; off < 64; off <<= 1) {
        s  += __shfl_xor(s, off);
        ss += __shfl_xor(ss, off);
    }
    __shared__ float rs[4], rss[4];
    const int wid = tid >> 6;
    if ((tid & 63) == 0) { rs[wid] = s; rss[wid] = ss; }
    __syncthreads();
    s  = rs[0] + rs[1] + rs[2] + rs[3];
    ss = rss[0] + rss[1] + rss[2] + rss[3];

    const float mu   = s * (1.f / (float)CDIM);
    const float var  = ss * (1.f / (float)CDIM) - mu * mu;
    const float rstd = rsqrtf(var + 1e-5f);

    const float4 g  = *(const float4*)&gamma[tid * 4];
    const float4 be = *(const float4*)&beta[tid * 4];
    float4 o;
    o.x = (v.x - mu) * rstd * g.x + be.x;
    o.y = (v.y - mu) * rstd * g.y + be.y;
    o.z = (v.z - mu) * rstd * g.z + be.z;
    o.w = (v.w - mu) * rstd * g.w + be.w;
    *(float4*)&out[(size_t)row * CDIM + tid * 4] = o;
}

// ---------------------------------------------------------------------------
extern "C" void kernel_launch(void* const* d_in, const int* in_sizes, int n_in,
                              void* d_out, int out_size, void* d_ws, size_t ws_size,
                              hipStream_t stream)
{
    const float* x      = (const float*)d_in[0];
    const float* W_emb  = (const float*)d_in[1];
    const float* b_emb  = (const float*)d_in[2];
    const float* pos    = (const float*)d_in[3];
    const float* Wqkv   = (const float*)d_in[4];
    const float* bqkv   = (const float*)d_in[5];
    const float* Wproj  = (const float*)d_in[6];
    const float* bproj  = (const float*)d_in[7];
    const float* gamma  = (const float*)d_in[8];
    const float* beta   = (const float*)d_in[9];
    const float* W_out  = (const float*)d_in[10];
    const float* b_out  = (const float*)d_in[11];
    float* out = (float*)d_out;

    float* h   = (float*)d_ws;                     // 4096*1024 f32
    float* qkv = h + (size_t)MROWS * CDIM;         // 4096*3072 (packed u32 in-place)
    float* y   = qkv + (size_t)MROWS * 3 * CDIM;   // 4096*1024 f32

    const dim3 blk(256);

    // h = x @ W_emb + b_emb + pos
    gemm_f32_kernel<<<dim3(CDIM / 64, MROWS / 64), blk, 0, stream>>>(
        x, W_emb, b_emb, pos, h, MROWS, CDIM, VDIM, T_SEQ, 0);

    for (int l = 0; l < NLAYER; ++l) {
        // qkv = split_pack(h @ Wqkv[l] + bqkv[l])
        gemm_f32_kernel<<<dim3(3 * CDIM / 64, MROWS / 64), blk, 0, stream>>>(
            h, Wqkv + (size_t)l * CDIM * 3 * CDIM, bqkv + (size_t)l * 3 * CDIM,
            nullptr, qkv, MROWS, 3 * CDIM, CDIM, 1, 1);
        // y = attention(qkv)
        attn_mfma_kernel<<<dim3(T_SEQ / 64, BATCH * NHEAD), blk, 0, stream>>>(
            (const uint*)qkv, y);
        // h = y @ Wproj[l] + bproj[l]
        gemm_f32_kernel<<<dim3(CDIM / 64, MROWS / 64), blk, 0, stream>>>(
            y, Wproj + (size_t)l * CDIM * CDIM, bproj + (size_t)l * CDIM,
            nullptr, h, MROWS, CDIM, CDIM, 1, 0);
    }

    ln_kernel<<<dim3(MROWS), blk, 0, stream>>>(h, gamma, beta, y);
    gemm_f32_kernel<<<dim3(VDIM / 64, MROWS / 64), blk, 0, stream>>>(
        y, W_out, b_out, nullptr, out, MROWS, VDIM, CDIM, 1, 0);
}

// Round 4
// 2533.472 us; speedup vs baseline: 4.3615x; 1.9006x over previous
//
#include <hip/hip_runtime.h>
#include <hip/hip_bf16.h>

#define T_SEQ 2048
#define BATCH 2
#define CDIM 1024
#define VDIM 256
#define NHEAD 16
#define DHEAD 64
#define NLAYER 8
#define MROWS (BATCH * T_SEQ) /* 4096 */

typedef __attribute__((ext_vector_type(8))) short bf16x8;
typedef __attribute__((ext_vector_type(4))) float f32x4;
typedef __attribute__((ext_vector_type(4))) int i32x4;

// v_perm_b32: sel byte 0-3 -> from 2nd arg, 4-7 -> from 1st arg
#define SELHI 0x07060302u  // top16(a)<<16 | top16(b)
#define SELLO 0x05040100u  // low16(a)<<16 | low16(b)

__device__ __forceinline__ uint prm(uint a, uint b, uint s) { return __builtin_amdgcn_perm(a, b, s); }

// round-to-nearest-even bf16 (as f32 with low mantissa zeroed)
__device__ __forceinline__ uint bf16rne(float f) {
    uint u = __float_as_uint(f);
    return (u + 0x7fffu + ((u >> 16) & 1u)) & 0xffff0000u;
}
// f32 -> (bf16 hi | bf16 lo) packed u32, both RNE. hi+lo ~= x to ~2^-16 rel.
__device__ __forceinline__ uint packsplit(float x) {
    uint hb = bf16rne(x);
    float d = x - __uint_as_float(hb);   // exact (Sterbenz)
    uint lb = bf16rne(d);
    return prm(hb, lb, SELHI);
}
__device__ __forceinline__ float unpack2(uint u) {
    return __uint_as_float(u & 0xffff0000u) + __uint_as_float(u << 16);
}
__device__ __forceinline__ bf16x8 asb(i32x4 v) {
    union { i32x4 i; bf16x8 b; } u; u.i = v; return u.b;
}

// ---------------------------------------------------------------------------
// f32 GEMM (embed / final out / fallback). out_mode 0: f32; 1: packed u32.
// addrow applied in BOTH modes (round-3 bug: out_mode 1 dropped pos).
// ---------------------------------------------------------------------------
__global__ __launch_bounds__(256) void gemm_f32_kernel(
    const float* __restrict__ A, const float* __restrict__ B,
    const float* __restrict__ bias, const float* __restrict__ addrow,
    float* __restrict__ C, int M, int N, int K, int addmod, int out_mode)
{
    __shared__ float As[16][64];
    __shared__ float Bs[16][68];

    const int tid = threadIdx.x;
    const int bn = blockIdx.x * 64;
    const int bm = blockIdx.y * 64;

    const int lrow = tid >> 2;
    const int lkq  = (tid & 3) * 4;
    const int lkr  = tid >> 4;
    const int lnq  = (tid & 15) * 4;
    const int ty   = tid >> 4;
    const int tx   = tid & 15;

    float acc[4][4];
#pragma unroll
    for (int i = 0; i < 4; ++i)
#pragma unroll
        for (int j = 0; j < 4; ++j) acc[i][j] = 0.f;

    for (int k0 = 0; k0 < K; k0 += 16) {
        __syncthreads();
        {
            float4 a4 = *(const float4*)&A[(size_t)(bm + lrow) * K + k0 + lkq];
            As[lkq + 0][lrow] = a4.x;
            As[lkq + 1][lrow] = a4.y;
            As[lkq + 2][lrow] = a4.z;
            As[lkq + 3][lrow] = a4.w;
            *(float4*)&Bs[lkr][lnq] =
                *(const float4*)&B[(size_t)(k0 + lkr) * N + bn + lnq];
        }
        __syncthreads();
#pragma unroll
        for (int kk = 0; kk < 16; ++kk) {
            const float4 a = *(const float4*)&As[kk][ty * 4];
            const float4 b = *(const float4*)&Bs[kk][tx * 4];
            acc[0][0] += a.x * b.x; acc[0][1] += a.x * b.y; acc[0][2] += a.x * b.z; acc[0][3] += a.x * b.w;
            acc[1][0] += a.y * b.x; acc[1][1] += a.y * b.y; acc[1][2] += a.y * b.z; acc[1][3] += a.y * b.w;
            acc[2][0] += a.z * b.x; acc[2][1] += a.z * b.y; acc[2][2] += a.z * b.z; acc[2][3] += a.z * b.w;
            acc[3][0] += a.w * b.x; acc[3][1] += a.w * b.y; acc[3][2] += a.w * b.z; acc[3][3] += a.w * b.w;
        }
    }

    const int ncol = bn + tx * 4;
    const float4 bv = *(const float4*)&bias[ncol];
#pragma unroll
    for (int i = 0; i < 4; ++i) {
        const int mrow = bm + ty * 4 + i;
        float4 o;
        o.x = acc[i][0] + bv.x;
        o.y = acc[i][1] + bv.y;
        o.z = acc[i][2] + bv.z;
        o.w = acc[i][3] + bv.w;
        if (addrow) {  // FIX: apply in both out modes
            const float4 p = *(const float4*)&addrow[(size_t)(mrow % addmod) * N + ncol];
            o.x += p.x; o.y += p.y; o.z += p.z; o.w += p.w;
        }
        if (out_mode == 0) {
            *(float4*)&C[(size_t)mrow * N + ncol] = o;
        } else {
            uint4 pk;
            pk.x = packsplit(o.x); pk.y = packsplit(o.y);
            pk.z = packsplit(o.z); pk.w = packsplit(o.w);
            *(uint4*)&((uint*)C)[(size_t)mrow * N + ncol] = pk;
        }
    }
}

// ---------------------------------------------------------------------------
// Weight pre-split: W[K][N] f32 -> frag-order hi/lo bf16 arrays
// F[n/16][k/32][64][8]: lane = gl*16 + (n&15), slot j: k = 4*gl + (j&3) + 16*(j>>2)
// ---------------------------------------------------------------------------
__global__ __launch_bounds__(256) void wsplit_kernel(
    const float* __restrict__ W, short* __restrict__ Fh, short* __restrict__ Fl,
    int N, int K)
{
    const int ln = threadIdx.x & 63, lk = threadIdx.x >> 6;
    const int n  = blockIdx.x * 64 + ln;
    const int kq = blockIdx.y * 4 + lk;
    const int k0 = kq * 4;

    float f0 = W[(size_t)(k0 + 0) * N + n];
    float f1 = W[(size_t)(k0 + 1) * N + n];
    float f2 = W[(size_t)(k0 + 2) * N + n];
    float f3 = W[(size_t)(k0 + 3) * N + n];
    uint h0 = bf16rne(f0), h1 = bf16rne(f1), h2 = bf16rne(f2), h3 = bf16rne(f3);
    uint l0 = bf16rne(f0 - __uint_as_float(h0));
    uint l1 = bf16rne(f1 - __uint_as_float(h1));
    uint l2 = bf16rne(f2 - __uint_as_float(h2));
    uint l3 = bf16rne(f3 - __uint_as_float(h3));

    const int gl = kq & 3, j0 = ((kq >> 2) & 1) * 4;
    const size_t base = (((size_t)(n >> 4) * (K >> 5) + (kq >> 3)) * 64 + gl * 16 + (n & 15)) * 8 + j0;
    *(int2*)&Fh[base] = make_int2((int)prm(h1, h0, SELHI), (int)prm(h3, h2, SELHI));
    *(int2*)&Fl[base] = make_int2((int)prm(l1, l0, SELHI), (int)prm(l3, l2, SELHI));
}

// ---------------------------------------------------------------------------
// MFMA bf16x2 GEMM: C[M,N] = A@B + bias. A packed u32 [M][K]; B pre-split
// frag-order. 128x128 tile, BK=32, 4 waves (2x2), 48 MFMA / K-step.
// ---------------------------------------------------------------------------
__global__ __launch_bounds__(256) void gemm_mfma_kernel(
    const uint* __restrict__ Ap, const short* __restrict__ Bhf,
    const short* __restrict__ Blf, const float* __restrict__ bias,
    void* __restrict__ Cv, int M, int N, int K, int out_mode)
{
    __shared__ __align__(16) short Ah[8][64][8], Al[8][64][8];
    __shared__ __align__(16) short Bh[8][64][8], Bl[8][64][8];

    const int tid = threadIdx.x, lane = tid & 63, w = tid >> 6;
    const int wr = w >> 1, wc = w & 1, x = lane & 15, gl = lane >> 4;
    const int bm = blockIdx.y * 128, bn = blockIdx.x * 128;
    const int nkc = K >> 5;

    f32x4 acc[4][4];
#pragma unroll
    for (int mi = 0; mi < 4; ++mi)
#pragma unroll
        for (int ni = 0; ni < 4; ++ni) acc[mi][ni] = (f32x4){0.f, 0.f, 0.f, 0.f};

    for (int kc = 0; kc < nkc; ++kc) {
        __syncthreads();
        // ---- stage B: pure copy, wave w handles chunks {w, w+4, w+8, w+12} ----
#pragma unroll
        for (int i = 0; i < 4; ++i) {
            const int c = i * 4 + w;             // wave-uniform
            const int hl = c >> 3, ni = c & 7;
            const short* src = (hl ? Blf : Bhf) +
                (((size_t)((bn >> 4) + ni) * nkc + kc) * 64 + lane) * 8;
            short* dst = (hl ? &Bl[0][0][0] : &Bh[0][0][0]) + ((size_t)ni * 64 + lane) * 8;
            *(int4*)dst = *(const int4*)src;
        }
        // ---- stage A: load packed u32, perm-split to hi/lo frag-linear ----
#pragma unroll
        for (int i = 0; i < 4; ++i) {
            const int f = i * 256 + tid;
            const int r = f >> 3, kq = f & 7;
            const uint4 a = *(const uint4*)&Ap[(size_t)(bm + r) * K + kc * 32 + kq * 4];
            const int mi = r >> 4, dl = (kq & 3) * 16 + (r & 15), j0 = (kq >> 2) * 4;
            *(int2*)&Ah[mi][dl][j0] = make_int2((int)prm(a.y, a.x, SELHI), (int)prm(a.w, a.z, SELHI));
            *(int2*)&Al[mi][dl][j0] = make_int2((int)prm(a.y, a.x, SELLO), (int)prm(a.w, a.z, SELLO));
        }
        __syncthreads();
        // ---- compute ----
        bf16x8 ah[4], al[4], bh[4], bl[4];
#pragma unroll
        for (int t = 0; t < 4; ++t) {
            ah[t] = *(const bf16x8*)&Ah[wr * 4 + t][lane][0];
            al[t] = *(const bf16x8*)&Al[wr * 4 + t][lane][0];
            bh[t] = *(const bf16x8*)&Bh[wc * 4 + t][lane][0];
            bl[t] = *(const bf16x8*)&Bl[wc * 4 + t][lane][0];
        }
#pragma unroll
        for (int mi = 0; mi < 4; ++mi)
#pragma unroll
            for (int ni = 0; ni < 4; ++ni) {
                acc[mi][ni] = __builtin_amdgcn_mfma_f32_16x16x32_bf16(ah[mi], bh[ni], acc[mi][ni], 0, 0, 0);
                acc[mi][ni] = __builtin_amdgcn_mfma_f32_16x16x32_bf16(ah[mi], bl[ni], acc[mi][ni], 0, 0, 0);
                acc[mi][ni] = __builtin_amdgcn_mfma_f32_16x16x32_bf16(al[mi], bh[ni], acc[mi][ni], 0, 0, 0);
            }
    }

    // ---- epilogue ----
#pragma unroll
    for (int ni = 0; ni < 4; ++ni) {
        const int n = bn + wc * 64 + ni * 16 + x;
        const float bv = bias[n];
#pragma unroll
        for (int mi = 0; mi < 4; ++mi) {
            const int m0 = bm + wr * 64 + mi * 16 + gl * 4;
            const f32x4 o = acc[mi][ni];
            if (out_mode == 0) {
                float* C = (float*)Cv;
                C[(size_t)(m0 + 0) * N + n] = o[0] + bv;
                C[(size_t)(m0 + 1) * N + n] = o[1] + bv;
                C[(size_t)(m0 + 2) * N + n] = o[2] + bv;
                C[(size_t)(m0 + 3) * N + n] = o[3] + bv;
            } else {
                uint* C = (uint*)Cv;
                C[(size_t)(m0 + 0) * N + n] = packsplit(o[0] + bv);
                C[(size_t)(m0 + 1) * N + n] = packsplit(o[1] + bv);
                C[(size_t)(m0 + 2) * N + n] = packsplit(o[2] + bv);
                C[(size_t)(m0 + 3) * N + n] = packsplit(o[3] + bv);
            }
        }
    }
}

// ---------------------------------------------------------------------------
// Flash attention MFMA bf16x2 (validated round 2; output optionally packed)
// ---------------------------------------------------------------------------
__global__ __launch_bounds__(256) void attn_mfma_kernel(
    const uint* __restrict__ qkv, void* __restrict__ y, int opack)
{
    __shared__ __align__(16) short khi[4][2][64][8];
    __shared__ __align__(16) short klo[4][2][64][8];
    __shared__ __align__(16) short vhi[4][2][64][8];
    __shared__ __align__(16) short vlo[4][2][64][8];
    __shared__ uint vpl[64][68];

    const int tid  = threadIdx.x;
    const int w    = tid >> 6;
    const int lane = tid & 63;
    const int x    = lane & 15;
    const int gl   = lane >> 4;
    const int bh = blockIdx.y, b = bh >> 4, hh = bh & 15;
    const int t0 = blockIdx.x * 64;

    i32x4 qhi[2], qlo[2];
    {
        const uint* qp = qkv + (size_t)(b * T_SEQ + t0 + 16 * w + x) * 3072 + hh * 64;
#pragma unroll
        for (int ch = 0; ch < 2; ++ch) {
            uint4 a0 = *(const uint4*)(qp + 32 * ch + 4 * gl);
            uint4 a1 = *(const uint4*)(qp + 32 * ch + 16 + 4 * gl);
            qhi[ch][0] = prm(a0.y, a0.x, SELHI); qhi[ch][1] = prm(a0.w, a0.z, SELHI);
            qhi[ch][2] = prm(a1.y, a1.x, SELHI); qhi[ch][3] = prm(a1.w, a1.z, SELHI);
            qlo[ch][0] = prm(a0.y, a0.x, SELLO); qlo[ch][1] = prm(a0.w, a0.z, SELLO);
            qlo[ch][2] = prm(a1.y, a1.x, SELLO); qlo[ch][3] = prm(a1.w, a1.z, SELLO);
        }
    }

    const int rK = tid >> 2, q4 = tid & 3;
    const int sc_s = rK >> 4, xk = rK & 15, chS = q4 >> 1, h2 = q4 & 1;

    f32x4 oacc[4];
#pragma unroll
    for (int i = 0; i < 4; ++i) oacc[i] = (f32x4){0.f, 0.f, 0.f, 0.f};
    float lsum = 0.f;

    for (int s0 = 0; s0 < T_SEQ; s0 += 64) {
        __syncthreads();
        {
            const uint* kp = qkv + (size_t)(b * T_SEQ + s0 + rK) * 3072 + 1024 + hh * 64 + 16 * q4;
            uint4 k0 = ((const uint4*)kp)[0], k1 = ((const uint4*)kp)[1];
            uint4 k2 = ((const uint4*)kp)[2], k3 = ((const uint4*)kp)[3];
            uint uu[16] = {k0.x, k0.y, k0.z, k0.w, k1.x, k1.y, k1.z, k1.w,
                           k2.x, k2.y, k2.z, k2.w, k3.x, k3.y, k3.z, k3.w};
#pragma unroll
            for (int g = 0; g < 4; ++g) {
                int2 hi2, lo2;
                hi2.x = (int)prm(uu[4 * g + 1], uu[4 * g + 0], SELHI);
                hi2.y = (int)prm(uu[4 * g + 3], uu[4 * g + 2], SELHI);
                lo2.x = (int)prm(uu[4 * g + 1], uu[4 * g + 0], SELLO);
                lo2.y = (int)prm(uu[4 * g + 3], uu[4 * g + 2], SELLO);
                *(int2*)&khi[sc_s][chS][16 * g + xk][4 * h2] = hi2;
                *(int2*)&klo[sc_s][chS][16 * g + xk][4 * h2] = lo2;
            }
            const uint* vp = qkv + (size_t)(b * T_SEQ + s0 + rK) * 3072 + 2048 + hh * 64 + 16 * q4;
            uint4 w0 = ((const uint4*)vp)[0], w1 = ((const uint4*)vp)[1];
            uint4 w2 = ((const uint4*)vp)[2], w3 = ((const uint4*)vp)[3];
            *(uint4*)&vpl[rK][16 * q4 + 0]  = w0;
            *(uint4*)&vpl[rK][16 * q4 + 4]  = w1;
            *(uint4*)&vpl[rK][16 * q4 + 8]  = w2;
            *(uint4*)&vpl[rK][16 * q4 + 12] = w3;
        }
        __syncthreads();
#pragma unroll
        for (int t2 = 0; t2 < 2; ++t2) {
            const int G = tid + 256 * t2;
            const int lt = G & 63, chv = (G >> 6) & 1, dm = G >> 7;
            const int glt = lt >> 4, xt = lt & 15, col = 16 * dm + xt;
            uint v0 = vpl[32 * chv + 4 * glt + 0][col];
            uint v1 = vpl[32 * chv + 4 * glt + 1][col];
            uint v2 = vpl[32 * chv + 4 * glt + 2][col];
            uint v3 = vpl[32 * chv + 4 * glt + 3][col];
            uint v4 = vpl[32 * chv + 4 * glt + 16][col];
            uint v5 = vpl[32 * chv + 4 * glt + 17][col];
            uint v6 = vpl[32 * chv + 4 * glt + 18][col];
            uint v7 = vpl[32 * chv + 4 * glt + 19][col];
            i32x4 hi4, lo4;
            hi4[0] = (int)prm(v1, v0, SELHI); hi4[1] = (int)prm(v3, v2, SELHI);
            hi4[2] = (int)prm(v5, v4, SELHI); hi4[3] = (int)prm(v7, v6, SELHI);
            lo4[0] = (int)prm(v1, v0, SELLO); lo4[1] = (int)prm(v3, v2, SELLO);
            lo4[2] = (int)prm(v5, v4, SELLO); lo4[3] = (int)prm(v7, v6, SELLO);
            *(i32x4*)&vhi[dm][chv][lt][0] = hi4;
            *(i32x4*)&vlo[dm][chv][lt][0] = lo4;
        }

        f32x4 pcur[4];
#pragma unroll
        for (int sc = 0; sc < 4; ++sc) {
            f32x4 s4 = (f32x4){0.f, 0.f, 0.f, 0.f};
#pragma unroll
            for (int ch = 0; ch < 2; ++ch) {
                bf16x8 kh = *(const bf16x8*)&khi[sc][ch][lane][0];
                bf16x8 kl = *(const bf16x8*)&klo[sc][ch][lane][0];
                s4 = __builtin_amdgcn_mfma_f32_16x16x32_bf16(kh, asb(qhi[ch]), s4, 0, 0, 0);
                s4 = __builtin_amdgcn_mfma_f32_16x16x32_bf16(kh, asb(qlo[ch]), s4, 0, 0, 0);
                s4 = __builtin_amdgcn_mfma_f32_16x16x32_bf16(kl, asb(qhi[ch]), s4, 0, 0, 0);
            }
            f32x4 p;
            p[0] = __expf(s4[0] * 0.125f);
            p[1] = __expf(s4[1] * 0.125f);
            p[2] = __expf(s4[2] * 0.125f);
            p[3] = __expf(s4[3] * 0.125f);
            lsum += p[0] + p[1] + p[2] + p[3];
            pcur[sc] = p;
        }

        i32x4 pfh[2], pfl[2];
#pragma unroll
        for (int c = 0; c < 2; ++c) {
            f32x4 pa = pcur[2 * c], pb = pcur[2 * c + 1];
            uint a0 = __float_as_uint(pa[0]), a1 = __float_as_uint(pa[1]);
            uint a2 = __float_as_uint(pa[2]), a3 = __float_as_uint(pa[3]);
            uint b0 = __float_as_uint(pb[0]), b1 = __float_as_uint(pb[1]);
            uint b2 = __float_as_uint(pb[2]), b3 = __float_as_uint(pb[3]);
            pfh[c][0] = (int)prm(a1, a0, SELHI); pfh[c][1] = (int)prm(a3, a2, SELHI);
            pfh[c][2] = (int)prm(b1, b0, SELHI); pfh[c][3] = (int)prm(b3, b2, SELHI);
            float d0 = pa[0] - __uint_as_float(a0 & 0xffff0000u);
            float d1 = pa[1] - __uint_as_float(a1 & 0xffff0000u);
            float d2 = pa[2] - __uint_as_float(a2 & 0xffff0000u);
            float d3 = pa[3] - __uint_as_float(a3 & 0xffff0000u);
            float e0 = pb[0] - __uint_as_float(b0 & 0xffff0000u);
            float e1 = pb[1] - __uint_as_float(b1 & 0xffff0000u);
            float e2 = pb[2] - __uint_as_float(b2 & 0xffff0000u);
            float e3 = pb[3] - __uint_as_float(b3 & 0xffff0000u);
            pfl[c][0] = (int)prm(__float_as_uint(d1), __float_as_uint(d0), SELHI);
            pfl[c][1] = (int)prm(__float_as_uint(d3), __float_as_uint(d2), SELHI);
            pfl[c][2] = (int)prm(__float_as_uint(e1), __float_as_uint(e0), SELHI);
            pfl[c][3] = (int)prm(__float_as_uint(e3), __float_as_uint(e2), SELHI);
        }
        __syncthreads();

#pragma unroll
        for (int dm = 0; dm < 4; ++dm) {
#pragma unroll
            for (int ch = 0; ch < 2; ++ch) {
                bf16x8 vh = *(const bf16x8*)&vhi[dm][ch][lane][0];
                bf16x8 vl = *(const bf16x8*)&vlo[dm][ch][lane][0];
                oacc[dm] = __builtin_amdgcn_mfma_f32_16x16x32_bf16(vh, asb(pfh[ch]), oacc[dm], 0, 0, 0);
                oacc[dm] = __builtin_amdgcn_mfma_f32_16x16x32_bf16(vh, asb(pfl[ch]), oacc[dm], 0, 0, 0);
                oacc[dm] = __builtin_amdgcn_mfma_f32_16x16x32_bf16(vl, asb(pfh[ch]), oacc[dm], 0, 0, 0);
            }
        }
    }

    lsum += __shfl_xor(lsum, 16);
    lsum += __shfl_xor(lsum, 32);
    const float invl = 1.f / lsum;

    const size_t orow = (size_t)(b * T_SEQ + t0 + 16 * w + x) * CDIM + hh * 64;
    if (opack) {
        uint* yp = (uint*)y + orow;
#pragma unroll
        for (int dm = 0; dm < 4; ++dm) {
            f32x4 o = oacc[dm];
            uint4 pk;
            pk.x = packsplit(o[0] * invl); pk.y = packsplit(o[1] * invl);
            pk.z = packsplit(o[2] * invl); pk.w = packsplit(o[3] * invl);
            *(uint4*)(yp + 16 * dm + 4 * gl) = pk;
        }
    } else {
        float* yp = (float*)y + orow;
#pragma unroll
        for (int dm = 0; dm < 4; ++dm) {
            f32x4 o = oacc[dm];
            o[0] *= invl; o[1] *= invl; o[2] *= invl; o[3] *= invl;
            *(f32x4*)(yp + 16 * dm + 4 * gl) = o;
        }
    }
}

// ---------------------------------------------------------------------------
// LayerNorm; input f32 or packed u32 per flag.
// ---------------------------------------------------------------------------
__global__ __launch_bounds__(256) void ln_kernel(
    const void* __restrict__ h, const float* __restrict__ gamma,
    const float* __restrict__ beta, float* __restrict__ out, int packed)
{
    const int row = blockIdx.x;
    const int tid = threadIdx.x;

    float4 v;
    if (packed) {
        uint4 u = *(const uint4*)&((const uint*)h)[(size_t)row * CDIM + tid * 4];
        v.x = unpack2(u.x); v.y = unpack2(u.y); v.z = unpack2(u.z); v.w = unpack2(u.w);
    } else {
        v = *(const float4*)&((const float*)h)[(size_t)row * CDIM + tid * 4];
    }
    float s  = v.x + v.y + v.z + v.w;
    float ss = v.x * v.x + v.y * v.y + v.z * v.z + v.w * v.w;
#pragma unroll
    for (int off = 1; off < 64; off <<= 1) {
        s  += __shfl_xor(s, off);
        ss += __shfl_xor(ss, off);
    }
    __shared__ float rs[4], rss[4];
    const int wid = tid >> 6;
    if ((tid & 63) == 0) { rs[wid] = s; rss[wid] = ss; }
    __syncthreads();
    s  = rs[0] + rs[1] + rs[2] + rs[3];
    ss = rss[0] + rss[1] + rss[2] + rss[3];

    const float mu   = s * (1.f / (float)CDIM);
    const float var  = ss * (1.f / (float)CDIM) - mu * mu;
    const float rstd = rsqrtf(var + 1e-5f);

    const float4 g  = *(const float4*)&gamma[tid * 4];
    const float4 be = *(const float4*)&beta[tid * 4];
    float4 o;
    o.x = (v.x - mu) * rstd * g.x + be.x;
    o.y = (v.y - mu) * rstd * g.y + be.y;
    o.z = (v.z - mu) * rstd * g.z + be.z;
    o.w = (v.w - mu) * rstd * g.w + be.w;
    *(float4*)&out[(size_t)row * CDIM + tid * 4] = o;
}

// ---------------------------------------------------------------------------
extern "C" void kernel_launch(void* const* d_in, const int* in_sizes, int n_in,
                              void* d_out, int out_size, void* d_ws, size_t ws_size,
                              hipStream_t stream)
{
    const float* x      = (const float*)d_in[0];
    const float* W_emb  = (const float*)d_in[1];
    const float* b_emb  = (const float*)d_in[2];
    const float* pos    = (const float*)d_in[3];
    const float* Wqkv   = (const float*)d_in[4];
    const float* bqkv   = (const float*)d_in[5];
    const float* Wproj  = (const float*)d_in[6];
    const float* bproj  = (const float*)d_in[7];
    const float* gamma  = (const float*)d_in[8];
    const float* beta   = (const float*)d_in[9];
    const float* W_out  = (const float*)d_in[10];
    const float* b_out  = (const float*)d_in[11];
    float* out = (float*)d_out;

    uint* h    = (uint*)d_ws;                      // [4096][1024] packed (or f32 in fallback)
    uint* qkvp = h + (size_t)MROWS * CDIM;         // [4096][3072] packed
    uint* y    = qkvp + (size_t)MROWS * 3 * CDIM;  // [4096][1024] packed / f32
    short* Bqh = (short*)(y + (size_t)MROWS * CDIM);
    short* Bql = Bqh + (size_t)3 * CDIM * CDIM;
    short* Bph = Bql + (size_t)3 * CDIM * CDIM;
    short* Bpl = Bph + (size_t)CDIM * CDIM;

    const size_t need = ((size_t)MROWS * CDIM * 5) * 4 +
                        ((size_t)3 * CDIM * CDIM * 2 + (size_t)CDIM * CDIM * 2) * 2;
    const bool use_mfma = ws_size >= need;

    const dim3 blk(256);

    if (use_mfma) {
        // h(packed) = x @ W_emb + b_emb + pos
        gemm_f32_kernel<<<dim3(CDIM / 64, MROWS / 64), blk, 0, stream>>>(
            x, W_emb, b_emb, pos, (float*)h, MROWS, CDIM, VDIM, T_SEQ, 1);
        for (int l = 0; l < NLAYER; ++l) {
            wsplit_kernel<<<dim3(3 * CDIM / 64, CDIM / 16), blk, 0, stream>>>(
                Wqkv + (size_t)l * CDIM * 3 * CDIM, Bqh, Bql, 3 * CDIM, CDIM);
            gemm_mfma_kernel<<<dim3(3 * CDIM / 128, MROWS / 128), blk, 0, stream>>>(
                h, Bqh, Bql, bqkv + (size_t)l * 3 * CDIM, qkvp, MROWS, 3 * CDIM, CDIM, 1);
            attn_mfma_kernel<<<dim3(T_SEQ / 64, BATCH * NHEAD), blk, 0, stream>>>(
                qkvp, y, 1);
            wsplit_kernel<<<dim3(CDIM / 64, CDIM / 16), blk, 0, stream>>>(
                Wproj + (size_t)l * CDIM * CDIM, Bph, Bpl, CDIM, CDIM);
            gemm_mfma_kernel<<<dim3(CDIM / 128, MROWS / 128), blk, 0, stream>>>(
                y, Bph, Bpl, bproj + (size_t)l * CDIM, h, MROWS, CDIM, CDIM, 1);
        }
        ln_kernel<<<dim3(MROWS), blk, 0, stream>>>(h, gamma, beta, (float*)y, 1);
    } else {
        // fallback: round-2 configuration (f32 GEMMs, f32 h/y, packed qkv only)
        gemm_f32_kernel<<<dim3(CDIM / 64, MROWS / 64), blk, 0, stream>>>(
            x, W_emb, b_emb, pos, (float*)h, MROWS, CDIM, VDIM, T_SEQ, 0);
        for (int l = 0; l < NLAYER; ++l) {
            gemm_f32_kernel<<<dim3(3 * CDIM / 64, MROWS / 64), blk, 0, stream>>>(
                (float*)h, Wqkv + (size_t)l * CDIM * 3 * CDIM, bqkv + (size_t)l * 3 * CDIM,
                nullptr, (float*)qkvp, MROWS, 3 * CDIM, CDIM, 1, 1);
            attn_mfma_kernel<<<dim3(T_SEQ / 64, BATCH * NHEAD), blk, 0, stream>>>(
                qkvp, y, 0);
            gemm_f32_kernel<<<dim3(CDIM / 64, MROWS / 64), blk, 0, stream>>>(
                (float*)y, Wproj + (size_t)l * CDIM * CDIM, bproj + (size_t)l * CDIM,
                nullptr, (float*)h, MROWS, CDIM, CDIM, 1, 0);
        }
        ln_kernel<<<dim3(MROWS), blk, 0, stream>>>(h, gamma, beta, (float*)y, 0);
    }

    gemm_f32_kernel<<<dim3(VDIM / 64, MROWS / 64), blk, 0, stream>>>(
        (float*)y, W_out, b_out, nullptr, out, MROWS, VDIM, CDIM, 1, 0);
}